// Round 1
// baseline (114.006 us; speedup 1.0000x reference)
//
#include <hip/hip_runtime.h>

// Ragged mean-pooling: [1024, 2048, 64] f32 -> [1024, 32, 64] f32.
// Segments per 256-field group: offsets {0,32,96,192}, sizes {32,64,96,64}, x8 groups.
// One wave per (batch, segment). float4 loads: lane t reads row f+(t>>4), cols (t&15)*4..+3.

__global__ __launch_bounds__(64) void meanpool_kernel(const float* __restrict__ emb,
                                                      float* __restrict__ out) {
    const int bs  = blockIdx.x;          // 0 .. 1024*32-1
    const int b   = bs >> 5;             // batch
    const int s   = bs & 31;             // segment
    const int grp = s >> 2;
    const int rem = s & 3;

    // static ragged layout
    const int off = (rem == 0) ? 0 : (rem == 1) ? 32 : (rem == 2) ? 96 : 192;
    const int sz  = (rem == 2) ? 96 : ((rem == 0) ? 32 : 64);
    const int fbase = grp * 256 + off;

    const int lane = threadIdx.x;        // 0..63
    const int row  = lane >> 4;          // 0..3  (field-row within a 4-row chunk)
    const int col4 = lane & 15;          // float4 column index (0..15), D/4 = 16

    // base of this segment's field rows: emb[b][fbase][0]
    const float4* __restrict__ src =
        reinterpret_cast<const float4*>(emb + ((size_t)b * 2048 + (size_t)fbase) * 64);

    float4 acc = make_float4(0.f, 0.f, 0.f, 0.f);
    // each iteration: wave reads 4 full field rows (4 x 256B = 1KiB, coalesced)
    #pragma unroll 4
    for (int f = row; f < sz; f += 4) {
        float4 v = src[(size_t)f * 16 + col4];
        acc.x += v.x; acc.y += v.y; acc.z += v.z; acc.w += v.w;
    }

    // reduce the 4 row-groups (lanes t, t^16, t^32, t^48 hold same columns)
    #pragma unroll
    for (int m = 16; m <= 32; m <<= 1) {
        acc.x += __shfl_xor(acc.x, m, 64);
        acc.y += __shfl_xor(acc.y, m, 64);
        acc.z += __shfl_xor(acc.z, m, 64);
        acc.w += __shfl_xor(acc.w, m, 64);
    }

    if (lane < 16) {
        const float inv = 1.0f / (float)sz;
        acc.x *= inv; acc.y *= inv; acc.z *= inv; acc.w *= inv;
        float4* __restrict__ dst =
            reinterpret_cast<float4*>(out + ((size_t)b * 32 + (size_t)s) * 64);
        dst[col4] = acc;
    }
}

extern "C" void kernel_launch(void* const* d_in, const int* in_sizes, int n_in,
                              void* d_out, int out_size, void* d_ws, size_t ws_size,
                              hipStream_t stream) {
    const float* emb = (const float*)d_in[0];
    float* out = (float*)d_out;
    const int num_blocks = 1024 * 32;   // one wave per (batch, segment)
    meanpool_kernel<<<dim3(num_blocks), dim3(64), 0, stream>>>(emb, out);
}

// Round 2
// 100.723 us; speedup vs baseline: 1.1319x; 1.1319x over previous
//
#include <hip/hip_runtime.h>

// Ragged mean-pooling: [1024, 2048, 64] f32 -> [1024, 32, 64] f32.
// Segments per 256-field group: offsets {0,32,96,192}, sizes {32,64,96,64}, x8 groups.
// One 256-thread block (4 waves) per (batch, group). Wave w owns segment w of the
// group; the block streams a contiguous 64 KiB input chunk. Lane t reads field-row
// f+(t>>4), float4 columns (t&15) -> 1 KiB coalesced per wave-load.

__global__ __launch_bounds__(256) void meanpool_kernel(const float* __restrict__ emb,
                                                       float* __restrict__ out) {
    const int bg  = blockIdx.x;          // 0 .. 1024*8-1
    const int b   = bg >> 3;             // batch
    const int grp = bg & 7;              // field-group (256 fields each)

    const int wave = threadIdx.x >> 6;   // 0..3 == segment index within group
    const int lane = threadIdx.x & 63;
    const int row  = lane >> 4;          // 0..3 field-row within a 4-row chunk
    const int col4 = lane & 15;          // float4 column (D/4 = 16)

    // static ragged layout within the 256-field group
    const int off = (wave == 0) ? 0 : (wave == 1) ? 32 : (wave == 2) ? 96 : 192;
    const int sz  = (wave == 2) ? 96 : ((wave == 0) ? 32 : 64);

    const float4* __restrict__ src =
        reinterpret_cast<const float4*>(emb + ((size_t)b * 2048 + (size_t)grp * 256 + off) * 64);

    float4 acc = make_float4(0.f, 0.f, 0.f, 0.f);
    // 8-deep unroll: up to 8 outstanding float4 loads per lane
    #pragma unroll 8
    for (int f = row; f < sz; f += 4) {
        float4 v = src[(size_t)f * 16 + col4];
        acc.x += v.x; acc.y += v.y; acc.z += v.z; acc.w += v.w;
    }

    // reduce across the 4 row-groups (lanes t, t^16, t^32, t^48 share columns)
    #pragma unroll
    for (int m = 16; m <= 32; m <<= 1) {
        acc.x += __shfl_xor(acc.x, m, 64);
        acc.y += __shfl_xor(acc.y, m, 64);
        acc.z += __shfl_xor(acc.z, m, 64);
        acc.w += __shfl_xor(acc.w, m, 64);
    }

    if (lane < 16) {
        const float inv = 1.0f / (float)sz;
        acc.x *= inv; acc.y *= inv; acc.z *= inv; acc.w *= inv;
        const int s = grp * 4 + wave;    // global segment id 0..31
        float4* __restrict__ dst =
            reinterpret_cast<float4*>(out + ((size_t)b * 32 + (size_t)s) * 64);
        dst[col4] = acc;
    }
}

extern "C" void kernel_launch(void* const* d_in, const int* in_sizes, int n_in,
                              void* d_out, int out_size, void* d_ws, size_t ws_size,
                              hipStream_t stream) {
    const float* emb = (const float*)d_in[0];
    float* out = (float*)d_out;
    const int num_blocks = 1024 * 8;     // one block per (batch, field-group)
    meanpool_kernel<<<dim3(num_blocks), dim3(256), 0, stream>>>(emb, out);
}

// Round 3
// 92.996 us; speedup vs baseline: 1.2259x; 1.0831x over previous
//
#include <hip/hip_runtime.h>

// Ragged mean-pooling: [1024, 2048, 64] f32 -> [1024, 32, 64] f32.
// Segments per 256-field group: offsets {0,32,96,192}, sizes {32,64,96,64}, x8.
// One 256-thread block per (batch, group). Waves are LOAD-BALANCED (16 float4
// loads each), aligned to segment boundaries:
//   wave0: seg0 rows 0-31  +  seg2 rows 96-127 (partial, combined via LDS)
//   wave1: seg1 rows 32-95
//   wave2: seg2 rows 128-191 (+ wave0's partial)
//   wave3: seg3 rows 192-255
// Lane t reads row base+(t>>4), float4 col (t&15) -> 1 KiB contiguous per wave-load.
// Input is streamed once -> nontemporal loads (skip L2 retention).

typedef float f32x4 __attribute__((ext_vector_type(4)));

__global__ __launch_bounds__(256) void meanpool_kernel(const float* __restrict__ emb,
                                                       float* __restrict__ out) {
    __shared__ f32x4 seg2_part[16];

    const int bg   = blockIdx.x;         // 0 .. 1024*8-1
    const int b    = bg >> 3;            // batch
    const int grp  = bg & 7;             // 256-field group
    const int wave = threadIdx.x >> 6;
    const int lane = threadIdx.x & 63;
    const int row  = lane >> 4;          // 0..3
    const int col4 = lane & 15;          // float4 column (D/4 = 16)

    const f32x4* __restrict__ src =
        reinterpret_cast<const f32x4*>(emb + ((size_t)b * 2048 + (size_t)grp * 256) * 64);
    // element (r, c): src[r*16 + c]

    f32x4 acc  = {0.f, 0.f, 0.f, 0.f};
    f32x4 acc2 = {0.f, 0.f, 0.f, 0.f};   // wave0 only: seg2 partial

    if (wave == 0) {
        #pragma unroll
        for (int f = 0; f < 32; f += 4)          // seg0
            acc  += __builtin_nontemporal_load(&src[(f + row) * 16 + col4]);
        #pragma unroll
        for (int f = 96; f < 128; f += 4)        // seg2 first half
            acc2 += __builtin_nontemporal_load(&src[(f + row) * 16 + col4]);
    } else {
        const int start = (wave == 1) ? 32 : (wave == 2) ? 128 : 192;
        #pragma unroll
        for (int k = 0; k < 64; k += 4)
            acc += __builtin_nontemporal_load(&src[(start + k + row) * 16 + col4]);
    }

    // butterfly across the 4 row-groups (lanes t, t^16, t^32, t^48 share a column)
    #pragma unroll
    for (int m = 16; m <= 32; m <<= 1) {
        acc.x += __shfl_xor(acc.x, m, 64);
        acc.y += __shfl_xor(acc.y, m, 64);
        acc.z += __shfl_xor(acc.z, m, 64);
        acc.w += __shfl_xor(acc.w, m, 64);
    }
    if (wave == 0) {
        #pragma unroll
        for (int m = 16; m <= 32; m <<= 1) {
            acc2.x += __shfl_xor(acc2.x, m, 64);
            acc2.y += __shfl_xor(acc2.y, m, 64);
            acc2.z += __shfl_xor(acc2.z, m, 64);
            acc2.w += __shfl_xor(acc2.w, m, 64);
        }
        if (lane < 16) seg2_part[col4] = acc2;
    }
    __syncthreads();

    if (lane < 16) {
        float inv;
        if (wave == 0)      inv = 1.0f / 32.0f;
        else if (wave == 2) { acc += seg2_part[col4]; inv = 1.0f / 96.0f; }
        else                inv = 1.0f / 64.0f;
        acc *= inv;
        const int s = grp * 4 + wave;    // global segment id
        f32x4* __restrict__ dst =
            reinterpret_cast<f32x4*>(out + ((size_t)b * 32 + (size_t)s) * 64);
        dst[col4] = acc;
    }
}

extern "C" void kernel_launch(void* const* d_in, const int* in_sizes, int n_in,
                              void* d_out, int out_size, void* d_ws, size_t ws_size,
                              hipStream_t stream) {
    const float* emb = (const float*)d_in[0];
    float* out = (float*)d_out;
    const int num_blocks = 1024 * 8;     // one block per (batch, field-group)
    meanpool_kernel<<<dim3(num_blocks), dim3(256), 0, stream>>>(emb, out);
}

// Round 4
// 90.363 us; speedup vs baseline: 1.2617x; 1.0291x over previous
//
#include <hip/hip_runtime.h>

// Ragged mean-pooling: [1024, 2048, 64] f32 -> [1024, 32, 64] f32.
// Segments per 256-field group: offsets {0,32,96,192}, sizes {32,64,96,64}, x8.
//
// One 256-thread block per (batch, PAIR of field-groups) -> 128 KiB contiguous.
// Per-wave segment pairing makes every wave do exactly 32 float4-load iters
// with NO cross-wave combine (no LDS, no __syncthreads -> no vmcnt(0) drain):
//   wave0: g0.seg0 (8 it) + g0.seg2 (24 it)
//   wave1: g0.seg1 (16)   + g0.seg3 (16)
//   wave2: g1.seg0 (8)    + g1.seg2 (24)
//   wave3: g1.seg1 (16)   + g1.seg3 (16)
// Lane t covers field-row base+(t>>4), float4 col (t&15): 1 KiB contiguous per
// wave-load. Input streamed once -> nontemporal loads.

typedef float f32x4 __attribute__((ext_vector_type(4)));

__global__ __launch_bounds__(256, 4) void meanpool_kernel(const float* __restrict__ emb,
                                                          float* __restrict__ out) {
    const int bg    = blockIdx.x;        // 0 .. 1024*4-1
    const int b     = bg >> 2;           // batch
    const int gpair = bg & 3;            // pair-of-groups index (0..3)

    const int wave  = threadIdx.x >> 6;  // 0..3
    const int lane  = threadIdx.x & 63;
    const int row   = lane >> 4;         // 0..3
    const int col4  = lane & 15;         // float4 column (D/4 = 16)

    const int grp   = gpair * 2 + (wave >> 1);   // waves {0,1}->g0, {2,3}->g1
    const bool even = (wave & 1) == 0;           // even: seg0+seg2, odd: seg1+seg3

    const f32x4* __restrict__ src =
        reinterpret_cast<const f32x4*>(emb + ((size_t)b * 2048 + (size_t)grp * 256) * 64);
    // element (r, c): src[r*16 + c]

    f32x4 accA = {0.f, 0.f, 0.f, 0.f};
    f32x4 accB = {0.f, 0.f, 0.f, 0.f};

    if (even) {
        #pragma unroll
        for (int f = 0; f < 32; f += 4)          // seg0: rows 0-31
            accA += __builtin_nontemporal_load(&src[(f + row) * 16 + col4]);
        #pragma unroll 8
        for (int f = 0; f < 96; f += 4)          // seg2: rows 96-191
            accB += __builtin_nontemporal_load(&src[(96 + f + row) * 16 + col4]);
    } else {
        #pragma unroll 8
        for (int f = 0; f < 64; f += 4)          // seg1: rows 32-95
            accA += __builtin_nontemporal_load(&src[(32 + f + row) * 16 + col4]);
        #pragma unroll 8
        for (int f = 0; f < 64; f += 4)          // seg3: rows 192-255
            accB += __builtin_nontemporal_load(&src[(192 + f + row) * 16 + col4]);
    }

    // butterfly across the 4 row-groups (lanes t, t^16, t^32, t^48 share a column)
    #pragma unroll
    for (int m = 16; m <= 32; m <<= 1) {
        accA.x += __shfl_xor(accA.x, m, 64);
        accA.y += __shfl_xor(accA.y, m, 64);
        accA.z += __shfl_xor(accA.z, m, 64);
        accA.w += __shfl_xor(accA.w, m, 64);
        accB.x += __shfl_xor(accB.x, m, 64);
        accB.y += __shfl_xor(accB.y, m, 64);
        accB.z += __shfl_xor(accB.z, m, 64);
        accB.w += __shfl_xor(accB.w, m, 64);
    }

    if (lane < 16) {
        const float invA = even ? (1.0f / 32.0f) : (1.0f / 64.0f);
        const float invB = even ? (1.0f / 96.0f) : (1.0f / 64.0f);
        const int sA = grp * 4 + (even ? 0 : 1);
        const int sB = grp * 4 + (even ? 2 : 3);
        f32x4* __restrict__ dstA =
            reinterpret_cast<f32x4*>(out + ((size_t)b * 32 + (size_t)sA) * 64);
        f32x4* __restrict__ dstB =
            reinterpret_cast<f32x4*>(out + ((size_t)b * 32 + (size_t)sB) * 64);
        dstA[col4] = accA * invA;
        dstB[col4] = accB * invB;
    }
}

extern "C" void kernel_launch(void* const* d_in, const int* in_sizes, int n_in,
                              void* d_out, int out_size, void* d_ws, size_t ws_size,
                              hipStream_t stream) {
    const float* emb = (const float*)d_in[0];
    float* out = (float*)d_out;
    const int num_blocks = 1024 * 4;     // one block per (batch, group-pair)
    meanpool_kernel<<<dim3(num_blocks), dim3(256), 0, stream>>>(emb, out);
}